// Round 3
// baseline (406.310 us; speedup 1.0000x reference)
//
#include <hip/hip_runtime.h>
#include <hip/hip_bf16.h>

#define BATCH 2048
#define NCLS 100000
#define DIM 128
#define SCALEF 10.0f
#define NT 782  // ceil(100000/128)

typedef __attribute__((ext_vector_type(8))) short bf16x8;
typedef __attribute__((ext_vector_type(4))) float f32x4;
typedef __attribute__((ext_vector_type(4))) int int4v;
typedef unsigned short u16;
typedef unsigned int u32;

static __device__ __forceinline__ float bf2f(u16 u) {
    union { u32 i; float f; } c; c.i = ((u32)u) << 16; return c.f;
}
static __device__ __forceinline__ u16 f2bf(float f) {
    union { float f; u32 i; } c; c.f = f;
    u32 x = c.i;
    x += ((x >> 16) & 1u) + 0x7FFFu;   // round-to-nearest-even
    return (u16)(x >> 16);
}

// ---------------- prep: normalize proxies -> bf16, psq from rounded ----------------
__global__ void prep_proxies_k(const float* __restrict__ proxies,
                               u16* __restrict__ pbf, float* __restrict__ psq) {
    int gid = blockIdx.x * 4 + (threadIdx.x >> 6);
    int lane = threadIdx.x & 63;
    const float2 v = *reinterpret_cast<const float2*>(proxies + (size_t)gid * DIM + lane * 2);
    float ss = v.x * v.x + v.y * v.y;
    #pragma unroll
    for (int off = 1; off < 64; off <<= 1) ss += __shfl_xor(ss, off);
    float rn = rsqrtf(ss);
    u16 b0 = f2bf(v.x * rn), b1 = f2bf(v.y * rn);
    *reinterpret_cast<u32*>(pbf + (size_t)gid * DIM + lane * 2) = (u32)b0 | ((u32)b1 << 16);
    float f0 = bf2f(b0), f1 = bf2f(b1);
    float s2 = f0 * f0 + f1 * f1;
    #pragma unroll
    for (int off = 1; off < 64; off <<= 1) s2 += __shfl_xor(s2, off);
    if (lane == 0) psq[gid] = s2;
}

// ---------------- prep: embeddings -> bf16, esq from rounded ----------------
__global__ void prep_embed_k(const float* __restrict__ emb,
                             u16* __restrict__ ebf, float* __restrict__ esq) {
    int gid = blockIdx.x * 4 + (threadIdx.x >> 6);
    int lane = threadIdx.x & 63;
    const float2 v = *reinterpret_cast<const float2*>(emb + (size_t)gid * DIM + lane * 2);
    u16 b0 = f2bf(v.x), b1 = f2bf(v.y);
    *reinterpret_cast<u32*>(ebf + (size_t)gid * DIM + lane * 2) = (u32)b0 | ((u32)b1 << 16);
    float f0 = bf2f(b0), f1 = bf2f(b1);
    float s2 = f0 * f0 + f1 * f1;
    #pragma unroll
    for (int off = 1; off < 64; off <<= 1) s2 += __shfl_xor(s2, off);
    if (lane == 0) esq[gid] = s2;
}

// ---------------- main: 128x128 tile GEMM + fused distance/partial-LSE ----------------
__global__ __launch_bounds__(256, 2)
void gemm_lse_k(const u16* __restrict__ pbf, const u16* __restrict__ ebf,
                const float* __restrict__ psq, const float* __restrict__ esq,
                float* __restrict__ pm, float* __restrict__ ps) {
    __shared__ char lA[128 * 256];  // 128 rows x 128 bf16 (256 B/row), XOR-swizzled
    __shared__ char lB[128 * 256];

    int bid = blockIdx.x;
    // bijective XCD swizzle: 12512 = 8 * 1564 -> contiguous chunk per XCD
    int nb = (bid & 7) * 1564 + (bid >> 3);
    int ct = nb >> 4;   // class tile 0..781
    int rt = nb & 15;   // row tile 0..15
    int tid = threadIdx.x;

    // stage A (embedding rows)
    #pragma unroll
    for (int i = 0; i < 8; ++i) {
        int idx = i * 256 + tid;
        int r = idx >> 4, kb = idx & 15;
        int grow = rt * 128 + r;
        int4v v = *reinterpret_cast<const int4v*>(ebf + (size_t)grow * DIM + kb * 8);
        int sw = (r * 256 + kb * 16) ^ ((r & 7) << 4);
        *reinterpret_cast<int4v*>(lA + sw) = v;
    }
    // stage B (proxy rows), zero-fill tail past NCLS
    #pragma unroll
    for (int i = 0; i < 8; ++i) {
        int idx = i * 256 + tid;
        int r = idx >> 4, kb = idx & 15;
        int gcls = ct * 128 + r;
        int4v v = {0, 0, 0, 0};
        if (gcls < NCLS) v = *reinterpret_cast<const int4v*>(pbf + (size_t)gcls * DIM + kb * 8);
        int sw = (r * 256 + kb * 16) ^ ((r & 7) << 4);
        *reinterpret_cast<int4v*>(lB + sw) = v;
    }
    __syncthreads();

    int wid = tid >> 6, lane = tid & 63;
    int l15 = lane & 15, lhi = lane >> 4;

    f32x4 zero = {0.0f, 0.0f, 0.0f, 0.0f};
    f32x4 acc[2][8];
    #pragma unroll
    for (int m = 0; m < 2; ++m)
        #pragma unroll
        for (int n = 0; n < 8; ++n) acc[m][n] = zero;

    #pragma unroll
    for (int kk = 0; kk < 4; ++kk) {
        int kbyte = kk * 64 + lhi * 16;
        bf16x8 a[2];
        #pragma unroll
        for (int m = 0; m < 2; ++m) {
            int r = wid * 32 + m * 16 + l15;
            a[m] = *reinterpret_cast<const bf16x8*>(lA + ((r * 256 + kbyte) ^ ((r & 7) << 4)));
        }
        #pragma unroll
        for (int n = 0; n < 8; ++n) {
            int c = n * 16 + l15;
            bf16x8 b = *reinterpret_cast<const bf16x8*>(lB + ((c * 256 + kbyte) ^ ((c & 7) << 4)));
            acc[0][n] = __builtin_amdgcn_mfma_f32_16x16x32_bf16(a[0], b, acc[0][n], 0, 0, 0);
            acc[1][n] = __builtin_amdgcn_mfma_f32_16x16x32_bf16(a[1], b, acc[1][n], 0, 0, 0);
        }
    }

    // epilogue: sim = -10*sqrt(max(esq+psq-2*dot,0)); per-row (max, sum-exp) over 128 cols
    float psqc[8];
    bool valid[8];
    #pragma unroll
    for (int n = 0; n < 8; ++n) {
        int gc = ct * 128 + n * 16 + l15;
        valid[n] = (gc < NCLS);
        psqc[n] = valid[n] ? psq[gc] : 0.0f;
    }
    #pragma unroll
    for (int m = 0; m < 2; ++m) {
        #pragma unroll
        for (int rg = 0; rg < 4; ++rg) {
            int grow = rt * 128 + wid * 32 + m * 16 + lhi * 4 + rg;
            float es = esq[grow];
            float sv[8];
            float mx = -1e30f;
            #pragma unroll
            for (int n = 0; n < 8; ++n) {
                float sq = es + psqc[n] - 2.0f * acc[m][n][rg];
                float s = -SCALEF * sqrtf(fmaxf(sq, 0.0f));
                if (!valid[n]) s = -1e30f;
                sv[n] = s;
                mx = fmaxf(mx, s);
            }
            #pragma unroll
            for (int off = 1; off < 16; off <<= 1) mx = fmaxf(mx, __shfl_xor(mx, off));
            float sum = 0.0f;
            #pragma unroll
            for (int n = 0; n < 8; ++n) sum += __expf(sv[n] - mx);
            #pragma unroll
            for (int off = 1; off < 16; off <<= 1) sum += __shfl_xor(sum, off);
            if (l15 == 0) {
                pm[(size_t)grow * NT + ct] = mx;
                ps[(size_t)grow * NT + ct] = sum;
            }
        }
    }
}

// ---------------- combine partials -> lse; pos term; weighted loss ----------------
__global__ void combine_k(const float* __restrict__ pm, const float* __restrict__ ps,
                          const u16* __restrict__ ebf, const u16* __restrict__ pbf,
                          const float* __restrict__ esq, const float* __restrict__ psq,
                          const int* __restrict__ labels, const float* __restrict__ cw,
                          float* __restrict__ out) {
    int row = blockIdx.x;
    int tid = threadIdx.x;
    float M = -1e30f, S = 0.0f;
    for (int t = tid; t < NT; t += 256) {
        float m = pm[(size_t)row * NT + t];
        float s = ps[(size_t)row * NT + t];
        if (m > M) { S = S * __expf(M - m) + s; M = m; }
        else       { S += s * __expf(m - M); }
    }
    __shared__ float sM[256], sS[256];
    __shared__ float sLse;
    sM[tid] = M; sS[tid] = S;
    __syncthreads();
    for (int st = 128; st > 0; st >>= 1) {
        if (tid < st) {
            float m1 = sM[tid], s1 = sS[tid];
            float m2 = sM[tid + st], s2 = sS[tid + st];
            float Mn = fmaxf(m1, m2);
            sM[tid] = Mn;
            sS[tid] = s1 * __expf(m1 - Mn) + s2 * __expf(m2 - Mn);
        }
        __syncthreads();
    }
    if (tid == 0) sLse = sM[0] + logf(sS[0]);
    __syncthreads();
    if (tid < 64) {
        int label = labels[row];
        u32 eu = *reinterpret_cast<const u32*>(ebf + (size_t)row * DIM + tid * 2);
        u32 pu = *reinterpret_cast<const u32*>(pbf + (size_t)label * DIM + tid * 2);
        float d = bf2f((u16)(eu & 0xFFFF)) * bf2f((u16)(pu & 0xFFFF))
                + bf2f((u16)(eu >> 16))    * bf2f((u16)(pu >> 16));
        #pragma unroll
        for (int off = 1; off < 64; off <<= 1) d += __shfl_xor(d, off);
        if (tid == 0) {
            float sq = esq[row] + psq[label] - 2.0f * d;
            float pos = -SCALEF * sqrtf(fmaxf(sq, 0.0f));
            float loss = (sLse - pos) * cw[label] * (1.0f / BATCH);
            atomicAdd(out, loss);
        }
    }
}

extern "C" void kernel_launch(void* const* d_in, const int* in_sizes, int n_in,
                              void* d_out, int out_size, void* d_ws, size_t ws_size,
                              hipStream_t stream) {
    const float* emb     = (const float*)d_in[0];
    const int*   labels  = (const int*)d_in[1];
    const float* cw      = (const float*)d_in[2];
    const float* proxies = (const float*)d_in[3];
    float* out = (float*)d_out;

    char* ws = (char*)d_ws;
    // layout (bytes):
    // pbf:  0          .. 25,600,000   (100000*128 bf16)
    // ebf:  25600000   .. 26,124,288   (2048*128 bf16)
    // psq:  26124288   .. 26,524,288   (100000 f32)
    // esq:  26524288   .. 26,532,480   (2048 f32)
    // pm:   26532480   .. 32,938,624   (2048*782 f32)
    // ps:   32938624   .. 39,344,768   (2048*782 f32)
    u16*   pbf = (u16*)ws;
    u16*   ebf = (u16*)(ws + 25600000);
    float* psq = (float*)(ws + 26124288);
    float* esq = (float*)(ws + 26524288);
    float* pm  = (float*)(ws + 26532480);
    float* ps  = (float*)(ws + 32938624);

    hipMemsetAsync(d_out, 0, sizeof(float), stream);
    prep_proxies_k<<<25000, 256, 0, stream>>>(proxies, pbf, psq);
    prep_embed_k<<<512, 256, 0, stream>>>(emb, ebf, esq);
    gemm_lse_k<<<12512, 256, 0, stream>>>(pbf, ebf, psq, esq, pm, ps);
    combine_k<<<2048, 256, 0, stream>>>(pm, ps, ebf, pbf, esq, psq, labels, cw, out);
}

// Round 5
// 282.102 us; speedup vs baseline: 1.4403x; 1.4403x over previous
//
#include <hip/hip_runtime.h>
#include <hip/hip_bf16.h>

#define BATCH 2048
#define NCLS 100000
#define DIM 128
#define SCALEF 10.0f
#define NT 782      // ceil(100000/128) class tiles
#define NCHUNK 196  // chunks of 4 tiles: 196*4 = 784 >= 782

typedef __attribute__((ext_vector_type(8))) short bf16x8;
typedef __attribute__((ext_vector_type(4))) float f32x4;
typedef unsigned short u16;
typedef unsigned int u32;

#if __has_builtin(__builtin_amdgcn_sqrtf)
#define FSQRT __builtin_amdgcn_sqrtf
#else
#define FSQRT sqrtf
#endif

static __device__ __forceinline__ float bf2f(u32 u) {
    union { u32 i; float f; } c; c.i = u << 16; return c.f;
}
static __device__ __forceinline__ u16 f2bf(float f) {
    union { float f; u32 i; } c; c.f = f;
    u32 x = c.i;
    x += ((x >> 16) & 1u) + 0x7FFFu;   // round-to-nearest-even
    return (u16)(x >> 16);
}

// ---------------- prep: normalize proxies -> bf16, psq from rounded ----------------
__global__ void prep_proxies_k(const float* __restrict__ proxies,
                               u16* __restrict__ pbf, float* __restrict__ psq) {
    int gid = blockIdx.x * 4 + (threadIdx.x >> 6);
    int lane = threadIdx.x & 63;
    const float2 v = *reinterpret_cast<const float2*>(proxies + (size_t)gid * DIM + lane * 2);
    float ss = v.x * v.x + v.y * v.y;
    #pragma unroll
    for (int off = 1; off < 64; off <<= 1) ss += __shfl_xor(ss, off);
    float rn = rsqrtf(ss);
    u16 b0 = f2bf(v.x * rn), b1 = f2bf(v.y * rn);
    *reinterpret_cast<u32*>(pbf + (size_t)gid * DIM + lane * 2) = (u32)b0 | ((u32)b1 << 16);
    float f0 = bf2f(b0), f1 = bf2f(b1);
    float s2 = f0 * f0 + f1 * f1;
    #pragma unroll
    for (int off = 1; off < 64; off <<= 1) s2 += __shfl_xor(s2, off);
    if (lane == 0) psq[gid] = s2;
}

// ---------------- prep: embeddings -> bf16, esq + analytic LSE shift ----------------
__global__ void prep_embed_k(const float* __restrict__ emb,
                             u16* __restrict__ ebf, float* __restrict__ esq,
                             float* __restrict__ negm0) {
    int gid = blockIdx.x * 4 + (threadIdx.x >> 6);
    int lane = threadIdx.x & 63;
    const float2 v = *reinterpret_cast<const float2*>(emb + (size_t)gid * DIM + lane * 2);
    u16 b0 = f2bf(v.x), b1 = f2bf(v.y);
    *reinterpret_cast<u32*>(ebf + (size_t)gid * DIM + lane * 2) = (u32)b0 | ((u32)b1 << 16);
    float f0 = bf2f(b0), f1 = bf2f(b1);
    float s2 = f0 * f0 + f1 * f1;
    #pragma unroll
    for (int off = 1; off < 64; off <<= 1) s2 += __shfl_xor(s2, off);
    if (lane == 0) {
        esq[gid] = s2;
        // M0 = -10*|sqrt(esq)-1| >= max sim over unit-norm proxies; negm0 = -M0 >= 0
        negm0[gid] = SCALEF * fabsf(sqrtf(s2) - 1.0f);
    }
}

// ---------------- main: per block 128 rows x (4 x 128-class tiles), fused LSE ----------------
__global__ __launch_bounds__(256, 3)
void gemm_lse_k(const u16* __restrict__ pbf, const u16* __restrict__ ebf,
                const float* __restrict__ psq, const float* __restrict__ esq,
                const float* __restrict__ negm0, float* __restrict__ ps) {
    // B tile: 128 classes x 128 bf16, LINEAR layout; conflict-free via pre-swizzled
    // global source (global_load_lds writes base+lane*16; reads XOR the chunk index).
    __shared__ __align__(16) u16 lB[128 * DIM];   // 32 KB

    int bid = blockIdx.x;
    int nb = (bid & 7) * 392 + (bid >> 3);   // bijective XCD swizzle, 3136 = 8*392
    int chunk = nb >> 4;                     // 0..195
    int rt = nb & 15;                        // 0..15
    int tid = threadIdx.x;
    int wid = tid >> 6, lane = tid & 63;
    int l15 = lane & 15, lhi = lane >> 4;
    int arowbase = rt * 128 + wid * 32;

    // issue B stage for tile 0 ASAP
    auto stage = [&](int c) {
        int ct128 = (chunk * 4 + c) * 128;
        #pragma unroll
        for (int j = 0; j < 8; ++j) {
            int r = wid * 32 + j * 4 + lhi;
            int kb = l15 ^ (r & 7);                       // pre-swizzled source chunk
            const u16* src = pbf + (size_t)(ct128 + r) * DIM + kb * 8;
            u32 ldsoff = (u32)(wid * 8192 + j * 1024);    // + lane*16 implied by HW
            __builtin_amdgcn_global_load_lds(
                (const __attribute__((address_space(1))) u32*)src,
                (__attribute__((address_space(3))) u32*)((char*)lB + ldsoff),
                16, 0, 0);
        }
    };
    stage(0);

    // A fragments in registers (reused across all 4 class tiles)
    bf16x8 afr[2][4];
    #pragma unroll
    for (int m = 0; m < 2; ++m) {
        const u16* arow = ebf + (size_t)(arowbase + m * 16 + l15) * DIM;
        #pragma unroll
        for (int kk = 0; kk < 4; ++kk)
            afr[m][kk] = *reinterpret_cast<const bf16x8*>(arow + kk * 32 + lhi * 8);
    }
    // per-thread row constants (8 rows each)
    float es[2][4], nm0[2][4], accs[2][4];
    #pragma unroll
    for (int m = 0; m < 2; ++m)
        #pragma unroll
        for (int rg = 0; rg < 4; ++rg) {
            int grow = arowbase + m * 16 + lhi * 4 + rg;
            es[m][rg] = esq[grow];
            nm0[m][rg] = negm0[grow];
            accs[m][rg] = 0.0f;
        }

    for (int c = 0; c < 4; ++c) {
        int ct = chunk * 4 + c;
        if (ct >= NT) break;               // block-uniform
        __syncthreads();                   // vmcnt(0) drain: B[c] staged

        f32x4 zero = {0.0f, 0.0f, 0.0f, 0.0f};
        f32x4 acc[2][8];
        #pragma unroll
        for (int m = 0; m < 2; ++m)
            #pragma unroll
            for (int n = 0; n < 8; ++n) acc[m][n] = zero;

        #pragma unroll
        for (int kk = 0; kk < 4; ++kk) {
            int kbyte = kk * 64 + lhi * 16;
            #pragma unroll
            for (int n = 0; n < 8; ++n) {
                int cc = n * 16 + l15;
                bf16x8 b = *reinterpret_cast<const bf16x8*>(
                    (const char*)lB + ((cc * 256 + kbyte) ^ ((cc & 7) << 4)));
                acc[0][n] = __builtin_amdgcn_mfma_f32_16x16x32_bf16(afr[0][kk], b, acc[0][n], 0, 0, 0);
                acc[1][n] = __builtin_amdgcn_mfma_f32_16x16x32_bf16(afr[1][kk], b, acc[1][n], 0, 0, 0);
            }
        }
        __syncthreads();                   // all waves done reading B[c]
        if (c < 3 && ct + 1 < NT) stage(c + 1);   // overlap next stage with epilogue

        // epilogue: accs += sum_n exp(-10*dist - M0); mask BEFORE exp (Inf*0=NaN trap)
        float psqc[8];
        bool valid[8];
        #pragma unroll
        for (int n = 0; n < 8; ++n) {
            int gc = ct * 128 + n * 16 + l15;
            valid[n] = (gc < NCLS);
            psqc[n] = psq[gc];             // tail reads land in ws (finite), masked below
        }
        #pragma unroll
        for (int m = 0; m < 2; ++m)
            #pragma unroll
            for (int rg = 0; rg < 4; ++rg) {
                float e2 = es[m][rg], nm = nm0[m][rg];
                float s = accs[m][rg];
                #pragma unroll
                for (int n = 0; n < 8; ++n) {
                    float sq = fmaf(-2.0f, acc[m][n][rg], e2 + psqc[n]);
                    float d = FSQRT(fmaxf(sq, 0.0f));
                    float t = fmaf(d, -SCALEF, nm);    // sim - M0  (<= ~0.05 for valid)
                    t = valid[n] ? t : -88.0f;         // mask pre-exp: exp(-88) ~= 0
                    s += __expf(t);
                }
                accs[m][rg] = s;
            }
    }

    // one reduction per kernel: fold 16 lanes (columns) per row, write chunk partial
    #pragma unroll
    for (int m = 0; m < 2; ++m)
        #pragma unroll
        for (int rg = 0; rg < 4; ++rg) {
            float s = accs[m][rg];
            #pragma unroll
            for (int off = 1; off < 16; off <<= 1) s += __shfl_xor(s, off);
            if (l15 == 0) {
                int grow = arowbase + m * 16 + lhi * 4 + rg;
                ps[(size_t)grow * NCHUNK + chunk] = s;
            }
        }
}

// ---------------- combine: lse = M0 + log(sum partials); pos term; weighted loss ----------------
__global__ __launch_bounds__(256)
void combine_k(const float* __restrict__ ps, const u16* __restrict__ ebf,
               const u16* __restrict__ pbf, const float* __restrict__ esq,
               const float* __restrict__ psq, const float* __restrict__ negm0,
               const int* __restrict__ labels, const float* __restrict__ cw,
               float* __restrict__ out) {
    int wid = threadIdx.x >> 6, lane = threadIdx.x & 63;
    int row = blockIdx.x * 4 + wid;
    float S = 0.0f;
    for (int t = lane; t < NCHUNK; t += 64) S += ps[(size_t)row * NCHUNK + t];
    #pragma unroll
    for (int off = 1; off < 64; off <<= 1) S += __shfl_xor(S, off);

    int label = labels[row];
    u32 eu = *reinterpret_cast<const u32*>(ebf + (size_t)row * DIM + lane * 2);
    u32 pu = *reinterpret_cast<const u32*>(pbf + (size_t)label * DIM + lane * 2);
    float d = bf2f(eu & 0xFFFFu) * bf2f(pu & 0xFFFFu)
            + bf2f(eu >> 16)     * bf2f(pu >> 16);
    #pragma unroll
    for (int off = 1; off < 64; off <<= 1) d += __shfl_xor(d, off);

    if (lane == 0) {
        float lse = -negm0[row] + logf(S);
        float sq = esq[row] + psq[label] - 2.0f * d;
        float pos = -SCALEF * FSQRT(fmaxf(sq, 0.0f));
        atomicAdd(out, (lse - pos) * cw[label] * (1.0f / BATCH));
    }
}

extern "C" void kernel_launch(void* const* d_in, const int* in_sizes, int n_in,
                              void* d_out, int out_size, void* d_ws, size_t ws_size,
                              hipStream_t stream) {
    const float* emb     = (const float*)d_in[0];
    const int*   labels  = (const int*)d_in[1];
    const float* cw      = (const float*)d_in[2];
    const float* proxies = (const float*)d_in[3];
    float* out = (float*)d_out;

    char* ws = (char*)d_ws;
    // layout (bytes):
    // pbf:   0          .. 25,600,000   (100000*128 bf16)
    // ebf:   25,600,000 .. 26,124,288   (2048*128 bf16)
    // esq:   26,124,288 .. 26,132,480   (2048 f32)
    // negm0: 26,132,480 .. 26,140,672   (2048 f32)
    // psq:   26,140,672 .. 26,540,672   (100000 f32)
    // ps:    26,540,672 .. 28,146,304   (2048*196 f32)
    u16*   pbf   = (u16*)ws;
    u16*   ebf   = (u16*)(ws + 25600000);
    float* esq   = (float*)(ws + 26124288);
    float* negm0 = (float*)(ws + 26132480);
    float* psq   = (float*)(ws + 26140672);
    float* ps    = (float*)(ws + 26540672);

    hipMemsetAsync(d_out, 0, sizeof(float), stream);
    prep_proxies_k<<<25000, 256, 0, stream>>>(proxies, pbf, psq);
    prep_embed_k<<<512, 256, 0, stream>>>(emb, ebf, esq, negm0);
    gemm_lse_k<<<3136, 256, 0, stream>>>(pbf, ebf, psq, esq, negm0, ps);
    combine_k<<<512, 256, 0, stream>>>(ps, ebf, pbf, esq, psq, negm0, labels, cw, out);
}